// Round 1
// baseline (862.752 us; speedup 1.0000x reference)
//
#include <hip/hip_runtime.h>

typedef __attribute__((ext_vector_type(8))) short bf16x8;
typedef __attribute__((ext_vector_type(4))) float f32x4;

#define BB 128
#define SS 8
#define CC 120
#define LL 469
#define HH 64

constexpr int NBATCH = SS * BB;        // 1024 (s,b) pairs; raw reshape => batch = s*B+b contiguous
constexpr int KSTEPS = (LL + 31) / 32; // 15

// ---- LDS layout ----
// phase 1: Xs[2][128][40] bf16 @0 (20480 B), Ws[2][192][40] bf16 @20480 (30720 B) -> 51200 B
// phase 2: Qs @0 (16 KB, [128] rows x 128 B, XOR-swz), Ks @16384, Vt @32768 ([64] x 256 B, swz)
//          P  @0 (32 KB, [128] x 256 B, swz) -- aliases Q+K after QK^T barrier
constexpr int XS_STRIDE = 40; // ushorts
constexpr int WS_STRIDE = 40;
constexpr int XS_BYTES = 128 * XS_STRIDE * 2; // 10240
constexpr int WS_BYTES = 192 * WS_STRIDE * 2; // 15360
constexpr int SMEM_BYTES = 2 * XS_BYTES + 2 * WS_BYTES; // 51200

__device__ __forceinline__ unsigned short f2bf(float f) {
  union { float f; unsigned u; } v; v.f = f;
  unsigned r = (v.u + 0x7FFFu + ((v.u >> 16) & 1u)) >> 16; // RNE
  return (unsigned short)r;
}

// XOR-swizzled LDS address: spreads 16B chunks of a row across banks (T2-style)
__device__ __forceinline__ char* sptr(char* base, int row, int stride, int byteoff) {
  return base + row * stride + (byteoff ^ ((row & 7) << 4));
}

__global__ __launch_bounds__(256, 2)
void fused_regional_head(const float* __restrict__ x,
                         const float* __restrict__ Wk,
                         const float* __restrict__ Wq,
                         const float* __restrict__ Wv,
                         float* __restrict__ out) {
  __shared__ char smem[SMEM_BYTES];
  const int tid = threadIdx.x;
  const int lane = tid & 63;
  const int wv = tid >> 6;   // wave 0..3, owns rows 32*wv .. 32*wv+31
  const int lr = lane & 15;
  const int lg = lane >> 4;
  const int batch = blockIdx.x;
  const size_t xbase = (size_t)batch * CC * LL;

  unsigned short* Xs = (unsigned short*)smem;
  unsigned short* Ws = (unsigned short*)(smem + 2 * XS_BYTES);

  auto stage = [&](int buf, int t) {
    const int k0 = t * 32;
    unsigned short* xb = Xs + buf * (128 * XS_STRIDE);
    unsigned short* wb = Ws + buf * (192 * WS_STRIDE);
    // X chunk: 128 rows x 32 k (rows >= 120 and k >= 469 zero-padded)
#pragma unroll
    for (int j = 0; j < 16; ++j) {
      int idx = j * 256 + tid;
      int row = idx >> 5, kk = idx & 31;
      int k = k0 + kk;
      float v = 0.f;
      if (row < CC && k < LL) v = x[xbase + (size_t)row * LL + k];
      xb[row * XS_STRIDE + kk] = f2bf(v);
    }
    // W chunk: cols 0..63=Wk, 64..127=Wq, 128..191=Wv, stored transposed [col][k]
#pragma unroll
    for (int j = 0; j < 24; ++j) {
      int idx = j * 256 + tid;
      int col = idx >> 5, kk = idx & 31;
      int k = k0 + kk;
      int wsel = col >> 6, h = col & 63;
      const float* wp = (wsel == 0) ? Wk : (wsel == 1) ? Wq : Wv;
      float v = (k < LL) ? wp[(size_t)k * HH + h] : 0.f;
      wb[col * WS_STRIDE + kk] = f2bf(v);
    }
  };

  // ---------------- phase 1: QKV = X @ [Wk|Wq|Wv] ----------------
  f32x4 acc[2][12];
#pragma unroll
  for (int m = 0; m < 2; ++m)
#pragma unroll
    for (int n = 0; n < 12; ++n) acc[m][n] = (f32x4){0.f, 0.f, 0.f, 0.f};

  stage(0, 0);
  for (int t = 0; t < KSTEPS; ++t) {
    __syncthreads(); // staging of buf (t&1) complete
    if (t + 1 < KSTEPS) stage((t + 1) & 1, t + 1);
    const unsigned short* xb = Xs + (t & 1) * (128 * XS_STRIDE);
    const unsigned short* wb = Ws + (t & 1) * (192 * WS_STRIDE);
    bf16x8 a0 = *(const bf16x8*)(xb + (wv * 32 + lr) * XS_STRIDE + lg * 8);
    bf16x8 a1 = *(const bf16x8*)(xb + (wv * 32 + 16 + lr) * XS_STRIDE + lg * 8);
#pragma unroll
    for (int n = 0; n < 12; ++n) {
      bf16x8 b = *(const bf16x8*)(wb + (n * 16 + lr) * WS_STRIDE + lg * 8);
      acc[0][n] = __builtin_amdgcn_mfma_f32_16x16x32_bf16(a0, b, acc[0][n], 0, 0, 0);
      acc[1][n] = __builtin_amdgcn_mfma_f32_16x16x32_bf16(a1, b, acc[1][n], 0, 0, 0);
    }
  }
  __syncthreads(); // all waves done reading staging buffers

  // ---------------- write Q,K,V (bf16, swizzled) ----------------
  char* Qb = smem;
  char* Kb = smem + 16384;
  char* Vb = smem + 32768;
  char* Pb = smem;
#pragma unroll
  for (int mt = 0; mt < 2; ++mt)
#pragma unroll
    for (int r = 0; r < 4; ++r) {
      int row = wv * 32 + mt * 16 + lg * 4 + r;
#pragma unroll
      for (int n = 0; n < 4; ++n) {
        *(unsigned short*)sptr(Kb, row, 128, (n * 16 + lr) * 2) = f2bf(acc[mt][n][r]);
        *(unsigned short*)sptr(Qb, row, 128, (n * 16 + lr) * 2) = f2bf(acc[mt][4 + n][r]);
        // V stored transposed: Vt[h][d_row]
        *(unsigned short*)sptr(Vb, n * 16 + lr, 256, row * 2) = f2bf(acc[mt][8 + n][r]);
      }
    }
  __syncthreads();

  // ---------------- QK^T ----------------
  f32x4 accw[2][8];
#pragma unroll
  for (int m = 0; m < 2; ++m)
#pragma unroll
    for (int n = 0; n < 8; ++n) accw[m][n] = (f32x4){0.f, 0.f, 0.f, 0.f};
#pragma unroll
  for (int ks = 0; ks < 2; ++ks) {
    bf16x8 a0 = *(const bf16x8*)sptr(Qb, wv * 32 + lr, 128, ks * 64 + lg * 16);
    bf16x8 a1 = *(const bf16x8*)sptr(Qb, wv * 32 + 16 + lr, 128, ks * 64 + lg * 16);
#pragma unroll
    for (int n = 0; n < 8; ++n) {
      bf16x8 b = *(const bf16x8*)sptr(Kb, n * 16 + lr, 128, ks * 64 + lg * 16);
      accw[0][n] = __builtin_amdgcn_mfma_f32_16x16x32_bf16(a0, b, accw[0][n], 0, 0, 0);
      accw[1][n] = __builtin_amdgcn_mfma_f32_16x16x32_bf16(a1, b, accw[1][n], 0, 0, 0);
    }
  }
  __syncthreads(); // everyone done reading Q/K before P overwrites them

  // ---------------- softmax (wave-parallel over 16-lane col groups) + P write ----------------
  const float sc = 0.125f; // 64^-0.5
#pragma unroll
  for (int mt = 0; mt < 2; ++mt)
#pragma unroll
    for (int r = 0; r < 4; ++r) {
      float l[8];
      float m = -1e30f;
#pragma unroll
      for (int n = 0; n < 8; ++n) {
        float v = accw[mt][n][r] * sc;
        if (n == 7 && lr >= 8) v = -1e30f; // col = 112+lr >= 120 -> masked
        l[n] = v;
        m = fmaxf(m, v);
      }
#pragma unroll
      for (int off = 1; off < 16; off <<= 1) m = fmaxf(m, __shfl_xor(m, off));
      float s = 0.f;
#pragma unroll
      for (int n = 0; n < 8; ++n) {
        float p = __expf(l[n] - m);
        l[n] = p;
        s += p;
      }
#pragma unroll
      for (int off = 1; off < 16; off <<= 1) s += __shfl_xor(s, off);
      float inv = 1.f / s;
      int row = wv * 32 + mt * 16 + lg * 4 + r;
#pragma unroll
      for (int n = 0; n < 8; ++n)
        *(unsigned short*)sptr(Pb, row, 256, (n * 16 + lr) * 2) = f2bf(l[n] * inv);
    }
  // no barrier needed: each wave reads only its own P rows; V was barrier-covered above

  // ---------------- out = P @ V ----------------
  f32x4 acco[2][4];
#pragma unroll
  for (int m = 0; m < 2; ++m)
#pragma unroll
    for (int n = 0; n < 4; ++n) acco[m][n] = (f32x4){0.f, 0.f, 0.f, 0.f};
#pragma unroll
  for (int ks = 0; ks < 4; ++ks) {
    bf16x8 a0 = *(const bf16x8*)sptr(Pb, wv * 32 + lr, 256, ks * 64 + lg * 16);
    bf16x8 a1 = *(const bf16x8*)sptr(Pb, wv * 32 + 16 + lr, 256, ks * 64 + lg * 16);
#pragma unroll
    for (int n = 0; n < 4; ++n) {
      bf16x8 b = *(const bf16x8*)sptr(Vb, n * 16 + lr, 256, ks * 64 + lg * 16);
      acco[0][n] = __builtin_amdgcn_mfma_f32_16x16x32_bf16(a0, b, acco[0][n], 0, 0, 0);
      acco[1][n] = __builtin_amdgcn_mfma_f32_16x16x32_bf16(a1, b, acco[1][n], 0, 0, 0);
    }
  }

  const size_t obase = (size_t)batch * CC * HH;
#pragma unroll
  for (int mt = 0; mt < 2; ++mt)
#pragma unroll
    for (int r = 0; r < 4; ++r) {
      int row = wv * 32 + mt * 16 + lg * 4 + r;
      if (row < CC) {
#pragma unroll
        for (int n = 0; n < 4; ++n)
          out[obase + (size_t)row * HH + n * 16 + lr] = acco[mt][n][r];
      }
    }
}

extern "C" void kernel_launch(void* const* d_in, const int* in_sizes, int n_in,
                              void* d_out, int out_size, void* d_ws, size_t ws_size,
                              hipStream_t stream) {
  (void)in_sizes; (void)n_in; (void)out_size; (void)d_ws; (void)ws_size;
  const float* x  = (const float*)d_in[0];
  const float* Wk = (const float*)d_in[1];
  const float* Wq = (const float*)d_in[2];
  const float* Wv = (const float*)d_in[3];
  float* out = (float*)d_out;
  fused_regional_head<<<NBATCH, 256, 0, stream>>>(x, Wk, Wq, Wv, out);
}

// Round 2
// 77.268 us; speedup vs baseline: 11.1656x; 11.1656x over previous
//
#include <hip/hip_runtime.h>

typedef __attribute__((ext_vector_type(8))) short bf16x8;
typedef __attribute__((ext_vector_type(4))) float f32x4;
typedef unsigned short ushort_t;

#define BB 128
#define SS 8
#define CC 120
#define LL 469
#define HH 64

constexpr int NBATCH = SS * BB;        // 1024 (s,b) pairs
constexpr int KSTEPS = (LL + 31) / 32; // 15

// ---- LDS layout ----
// phase 1: Xf[2][128][32] f32 @0 (32768 B, rows 120..127 zeroed once),
//          Wl[2][192][40] bf16 @32768 (30720 B)  -> 63488 B
// phase 2: Qb @0 (16 KB, [128]x128B swz), Kb @16384, Vb @32768 ([64]x256B swz)
//          Pb @0 (32 KB, [128]x256B swz) aliases Q+K after QK^T barrier
constexpr int XBUF_FLOATS = 128 * 32;            // one buffer
constexpr int XBUF_BYTES  = XBUF_FLOATS * 4;     // 16384
constexpr int WBUF_SHORTS = 192 * 40;
constexpr int WBUF_BYTES  = WBUF_SHORTS * 2;     // 15360
constexpr int SMEM_BYTES  = 2 * XBUF_BYTES + 2 * WBUF_BYTES; // 63488
constexpr int WIMG_BYTES  = KSTEPS * WBUF_BYTES; // 230400

__device__ __forceinline__ ushort_t f2bf(float f) {
  union { float f; unsigned u; } v; v.f = f;
  unsigned r = (v.u + 0x7FFFu + ((v.u >> 16) & 1u)) >> 16; // RNE
  return (ushort_t)r;
}

__device__ __forceinline__ void gload_lds4(const void* g, void* l) {
  __builtin_amdgcn_global_load_lds(
      (const __attribute__((address_space(1))) unsigned int*)g,
      (__attribute__((address_space(3))) unsigned int*)l, 4, 0, 0);
}
__device__ __forceinline__ void gload_lds16(const void* g, void* l) {
  __builtin_amdgcn_global_load_lds(
      (const __attribute__((address_space(1))) unsigned int*)g,
      (__attribute__((address_space(3))) unsigned int*)l, 16, 0, 0);
}

// XOR-swizzled LDS address for phase-2 tiles
__device__ __forceinline__ char* sptr(char* base, int row, int stride, int byteoff) {
  return base + row * stride + (byteoff ^ ((row & 7) << 4));
}

__global__ void prep_w(const float* __restrict__ Wk, const float* __restrict__ Wq,
                       const float* __restrict__ Wv, ushort_t* __restrict__ wimg) {
  int idx = blockIdx.x * 256 + threadIdx.x; // 15*192*40 = 115200 exactly
  int t = idx / (192 * 40);
  int rem = idx % (192 * 40);
  int col = rem / 40;
  int kk = rem % 40;
  int k = t * 32 + kk;
  int wsel = col >> 6, h = col & 63;
  const float* wp = (wsel == 0) ? Wk : (wsel == 1) ? Wq : Wv;
  float v = (kk < 32 && k < LL) ? wp[(size_t)k * HH + h] : 0.f;
  wimg[idx] = f2bf(v);
}

template <bool WIMG>
__global__ __launch_bounds__(256, 2)
void fused_regional_head(const float* __restrict__ x,
                         const float* __restrict__ Wk,
                         const float* __restrict__ Wq,
                         const float* __restrict__ Wv,
                         const ushort_t* __restrict__ wimg,
                         float* __restrict__ out) {
  __shared__ char smem[SMEM_BYTES];
  const int tid = threadIdx.x;
  const int lane = tid & 63;
  const int wv = tid >> 6;   // wave 0..3, owns rows 32*wv .. 32*wv+31
  const int lr = lane & 15;
  const int lg = lane >> 4;
  const int batch = blockIdx.x;
  const size_t xbase = (size_t)batch * CC * LL;

  float* Xf = (float*)smem;                                // [2][128][32]
  ushort_t* Wl = (ushort_t*)(smem + 2 * XBUF_BYTES);       // [2][192][40]

  // zero pad rows 120..127 of both X buffers (never re-staged)
  Xf[0 * XBUF_FLOATS + 120 * 32 + tid] = 0.f;
  Xf[1 * XBUF_FLOATS + 120 * 32 + tid] = 0.f;

  // X stage: rows 0..119, 32 k-words each. LDS is linear; source address is
  // chunk-XOR-swizzled so later ds_read_b128 of 16B chunk s reads phys s^(row&7).
  auto stage_x = [&](int buf, int t) {
    const int k0 = t * 32;
    float* dst = Xf + buf * XBUF_FLOATS;
#pragma unroll
    for (int i = 0; i < 15; ++i) {
      int slot = i * 4 + wv;              // 0..59, 64 dwords each
      int dw = slot * 64 + lane;          // dword index in [0,3840)
      int row = dw >> 5;
      int w = dw & 31;
      int s = w >> 2, q = w & 3;
      int lw = ((s ^ (row & 7)) << 2) | q; // logical k-word
      int k = k0 + lw;
      if (k < LL) {
        gload_lds4(x + xbase + (size_t)row * LL + k, dst + slot * 64);
      } else {
        dst[dw] = 0.f; // tail step zero-fill
      }
    }
  };

  auto stage_w = [&](int buf, int t) {
    ushort_t* wb = Wl + buf * WBUF_SHORTS;
    if constexpr (WIMG) {
      const char* src = (const char*)(wimg + t * WBUF_SHORTS);
#pragma unroll
      for (int i = 0; i < 4; ++i) {
        int c = wv + 4 * i; // 1024-byte chunks, 15 total
        if (c < 15) gload_lds16(src + c * 1024 + lane * 16, (char*)wb + c * 1024);
      }
    } else {
      const int k0 = t * 32;
#pragma unroll
      for (int j = 0; j < 24; ++j) {
        int idx = j * 256 + tid;
        int col = idx >> 5, kk = idx & 31;
        int k = k0 + kk;
        int wsel = col >> 6, h = col & 63;
        const float* wp = (wsel == 0) ? Wk : (wsel == 1) ? Wq : Wv;
        float v = (k < LL) ? wp[(size_t)k * HH + h] : 0.f;
        wb[col * 40 + kk] = f2bf(v);
      }
    }
  };

  // A-fragment: 8 logical k-words (2 swizzled 16B chunks), fp32 -> bf16
  auto loadA = [&](const float* xb, int row) -> bf16x8 {
    int s0 = (lg * 2) ^ (row & 7);
    int s1 = (lg * 2 + 1) ^ (row & 7);
    f32x4 c0 = *(const f32x4*)(xb + row * 32 + s0 * 4);
    f32x4 c1 = *(const f32x4*)(xb + row * 32 + s1 * 4);
    bf16x8 r;
    r[0] = (short)f2bf(c0[0]); r[1] = (short)f2bf(c0[1]);
    r[2] = (short)f2bf(c0[2]); r[3] = (short)f2bf(c0[3]);
    r[4] = (short)f2bf(c1[0]); r[5] = (short)f2bf(c1[1]);
    r[6] = (short)f2bf(c1[2]); r[7] = (short)f2bf(c1[3]);
    return r;
  };

  // ---------------- phase 1: QKV = X @ [Wk|Wq|Wv] ----------------
  f32x4 acc[2][12];
#pragma unroll
  for (int m = 0; m < 2; ++m)
#pragma unroll
    for (int n = 0; n < 12; ++n) acc[m][n] = (f32x4){0.f, 0.f, 0.f, 0.f};

  stage_x(0, 0);
  stage_w(0, 0);
  for (int t = 0; t < KSTEPS; ++t) {
    __syncthreads(); // staging of buf (t&1) complete (vmcnt drained at barrier)
    if (t + 1 < KSTEPS) { stage_x((t + 1) & 1, t + 1); stage_w((t + 1) & 1, t + 1); }
    const float* xb = Xf + (t & 1) * XBUF_FLOATS;
    const ushort_t* wb = Wl + (t & 1) * WBUF_SHORTS;
    bf16x8 a0 = loadA(xb, wv * 32 + lr);
    bf16x8 a1 = loadA(xb, wv * 32 + 16 + lr);
#pragma unroll
    for (int n = 0; n < 12; ++n) {
      bf16x8 b = *(const bf16x8*)(wb + (n * 16 + lr) * 40 + lg * 8);
      acc[0][n] = __builtin_amdgcn_mfma_f32_16x16x32_bf16(a0, b, acc[0][n], 0, 0, 0);
      acc[1][n] = __builtin_amdgcn_mfma_f32_16x16x32_bf16(a1, b, acc[1][n], 0, 0, 0);
    }
  }
  __syncthreads(); // all waves done reading staging buffers

  // ---------------- write Q,K,V (bf16, swizzled) ----------------
  char* Qb = smem;
  char* Kb = smem + 16384;
  char* Vb = smem + 32768;
  char* Pb = smem;
#pragma unroll
  for (int mt = 0; mt < 2; ++mt)
#pragma unroll
    for (int r = 0; r < 4; ++r) {
      int row = wv * 32 + mt * 16 + lg * 4 + r;
#pragma unroll
      for (int n = 0; n < 4; ++n) {
        *(ushort_t*)sptr(Kb, row, 128, (n * 16 + lr) * 2) = f2bf(acc[mt][n][r]);
        *(ushort_t*)sptr(Qb, row, 128, (n * 16 + lr) * 2) = f2bf(acc[mt][4 + n][r]);
        *(ushort_t*)sptr(Vb, n * 16 + lr, 256, row * 2) = f2bf(acc[mt][8 + n][r]); // V^T
      }
    }
  __syncthreads();

  // ---------------- QK^T ----------------
  f32x4 accw[2][8];
#pragma unroll
  for (int m = 0; m < 2; ++m)
#pragma unroll
    for (int n = 0; n < 8; ++n) accw[m][n] = (f32x4){0.f, 0.f, 0.f, 0.f};
#pragma unroll
  for (int ks = 0; ks < 2; ++ks) {
    bf16x8 a0 = *(const bf16x8*)sptr(Qb, wv * 32 + lr, 128, ks * 64 + lg * 16);
    bf16x8 a1 = *(const bf16x8*)sptr(Qb, wv * 32 + 16 + lr, 128, ks * 64 + lg * 16);
#pragma unroll
    for (int n = 0; n < 8; ++n) {
      bf16x8 b = *(const bf16x8*)sptr(Kb, n * 16 + lr, 128, ks * 64 + lg * 16);
      accw[0][n] = __builtin_amdgcn_mfma_f32_16x16x32_bf16(a0, b, accw[0][n], 0, 0, 0);
      accw[1][n] = __builtin_amdgcn_mfma_f32_16x16x32_bf16(a1, b, accw[1][n], 0, 0, 0);
    }
  }
  __syncthreads(); // everyone done reading Q/K before P overwrites them

  // ---------------- softmax (wave-parallel over 16-lane col groups) ----------------
  const float sc = 0.125f; // 64^-0.5
#pragma unroll
  for (int mt = 0; mt < 2; ++mt)
#pragma unroll
    for (int r = 0; r < 4; ++r) {
      float l[8];
      float m = -1e30f;
#pragma unroll
      for (int n = 0; n < 8; ++n) {
        float v = accw[mt][n][r] * sc;
        if (n == 7 && lr >= 8) v = -1e30f; // col = 112+lr >= 120 masked
        l[n] = v;
        m = fmaxf(m, v);
      }
#pragma unroll
      for (int off = 1; off < 16; off <<= 1) m = fmaxf(m, __shfl_xor(m, off));
      float s = 0.f;
#pragma unroll
      for (int n = 0; n < 8; ++n) {
        float p = __expf(l[n] - m);
        l[n] = p;
        s += p;
      }
#pragma unroll
      for (int off = 1; off < 16; off <<= 1) s += __shfl_xor(s, off);
      float inv = 1.f / s;
      int row = wv * 32 + mt * 16 + lg * 4 + r;
#pragma unroll
      for (int n = 0; n < 8; ++n)
        *(ushort_t*)sptr(Pb, row, 256, (n * 16 + lr) * 2) = f2bf(l[n] * inv);
    }
  // no barrier: each wave reads only its own P rows; V covered by barrier above

  // ---------------- out = P @ V ----------------
  f32x4 acco[2][4];
#pragma unroll
  for (int m = 0; m < 2; ++m)
#pragma unroll
    for (int n = 0; n < 4; ++n) acco[m][n] = (f32x4){0.f, 0.f, 0.f, 0.f};
#pragma unroll
  for (int ks = 0; ks < 4; ++ks) {
    bf16x8 a0 = *(const bf16x8*)sptr(Pb, wv * 32 + lr, 256, ks * 64 + lg * 16);
    bf16x8 a1 = *(const bf16x8*)sptr(Pb, wv * 32 + 16 + lr, 256, ks * 64 + lg * 16);
#pragma unroll
    for (int n = 0; n < 4; ++n) {
      bf16x8 b = *(const bf16x8*)sptr(Vb, n * 16 + lr, 256, ks * 64 + lg * 16);
      acco[0][n] = __builtin_amdgcn_mfma_f32_16x16x32_bf16(a0, b, acco[0][n], 0, 0, 0);
      acco[1][n] = __builtin_amdgcn_mfma_f32_16x16x32_bf16(a1, b, acco[1][n], 0, 0, 0);
    }
  }

  const size_t obase = (size_t)batch * CC * HH;
#pragma unroll
  for (int mt = 0; mt < 2; ++mt)
#pragma unroll
    for (int r = 0; r < 4; ++r) {
      int row = wv * 32 + mt * 16 + lg * 4 + r;
      if (row < CC) {
#pragma unroll
        for (int n = 0; n < 4; ++n)
          out[obase + (size_t)row * HH + n * 16 + lr] = acco[mt][n][r];
      }
    }
}

extern "C" void kernel_launch(void* const* d_in, const int* in_sizes, int n_in,
                              void* d_out, int out_size, void* d_ws, size_t ws_size,
                              hipStream_t stream) {
  (void)in_sizes; (void)n_in; (void)out_size;
  const float* x  = (const float*)d_in[0];
  const float* Wk = (const float*)d_in[1];
  const float* Wq = (const float*)d_in[2];
  const float* Wv = (const float*)d_in[3];
  float* out = (float*)d_out;
  if (ws_size >= (size_t)WIMG_BYTES && d_ws != nullptr) {
    ushort_t* wimg = (ushort_t*)d_ws;
    prep_w<<<450, 256, 0, stream>>>(Wk, Wq, Wv, wimg);
    fused_regional_head<true><<<NBATCH, 256, 0, stream>>>(x, Wk, Wq, Wv, wimg, out);
  } else {
    fused_regional_head<false><<<NBATCH, 256, 0, stream>>>(x, Wk, Wq, Wv, nullptr, out);
  }
}